// Round 10
// baseline (910.385 us; speedup 1.0000x reference)
//
#include <hip/hip_runtime.h>
#include <hip/hip_bf16.h>
#include <stdint.h>

#define T_TOK 8192
#define H_DIM 1024
#define F_DIM 4096
#define NEXP  8
#define CAP        17408   // 16384 + 8*128 worst-case 128-aligned padding
#define CT128      136     // CAP/128

typedef __attribute__((ext_vector_type(8))) short bf16x8;
typedef __attribute__((ext_vector_type(4))) float f32x4;

#define AS1 __attribute__((address_space(1)))
#define AS3 __attribute__((address_space(3)))

__device__ __forceinline__ void gload_lds16(const void* g, void* l) {
  __builtin_amdgcn_global_load_lds((const AS1 void*)g, (AS3 void*)l, 16, 0, 0);
}

// expert of a 128-row tile, from counts (128-aligned segments)
__device__ __forceinline__ int tile_expert_of(const int* counts, int tm) {
  int row = tm * 128, off = 0, e = NEXP - 1;
#pragma unroll
  for (int k = 0; k < NEXP; ++k) {
    int nxt = off + ((counts[k] + 127) & ~127);
    if (row >= off && row < nxt) { e = k; break; }
    off = nxt;
  }
  return e;
}

struct TK { int i0, i1; float w0, w1; };

// ---------------- router: fp32 logits, softmax, top-2, renorm ----------------
__global__ __launch_bounds__(256) void router_kernel(
    const float* __restrict__ x, const float* __restrict__ gw,
    float* __restrict__ logits, int* __restrict__ counts, TK* __restrict__ tk)
{
  const int lane = threadIdx.x & 63;
  const int t = blockIdx.x * 4 + (threadIdx.x >> 6);
  const float* xp = x + (size_t)t * H_DIM;
  float xr[16];
#pragma unroll
  for (int i = 0; i < 16; ++i) xr[i] = xp[lane + i * 64];
  float lg[NEXP];
#pragma unroll
  for (int e = 0; e < NEXP; ++e) {
    const float* gp = gw + e * H_DIM;
    float acc = 0.f;
#pragma unroll
    for (int i = 0; i < 16; ++i) acc += xr[i] * gp[lane + i * 64];
#pragma unroll
    for (int s = 32; s > 0; s >>= 1) acc += __shfl_xor(acc, s, 64);
    lg[e] = acc;
  }
  if (lane < NEXP) logits[(size_t)t * NEXP + lane] = lg[lane];
  if (lane == 0) {
    int i0 = 0; float m0 = lg[0];
#pragma unroll
    for (int e = 1; e < NEXP; ++e) if (lg[e] > m0) { m0 = lg[e]; i0 = e; }
    int i1 = -1; float m1 = -1e30f;
#pragma unroll
    for (int e = 0; e < NEXP; ++e) if (e != i0 && lg[e] > m1) { m1 = lg[e]; i1 = e; }
    float r = expf(m1 - m0);            // top-2 renormalized softmax
    float w0 = 1.f / (1.f + r);
    float w1 = r / (1.f + r);
    TK v; v.i0 = i0; v.i1 = i1; v.w0 = w0; v.w1 = w1;
    tk[t] = v;
    atomicAdd(&counts[i0], 1);
    atomicAdd(&counts[i1], 1);
  }
}

// ---------------- scatter: token -> slot (offsets computed inline) ----------
__global__ __launch_bounds__(256) void scatter_kernel(
    const TK* __restrict__ tk, const int* __restrict__ counts,
    int* __restrict__ cursor, int* __restrict__ pair_tok,
    float* __restrict__ pair_w, int2* __restrict__ inv)
{
  int t = blockIdx.x * 256 + threadIdx.x;
  if (t >= T_TOK) return;
  int offs[NEXP];
  int o = 0;
#pragma unroll
  for (int e = 0; e < NEXP; ++e) { offs[e] = o; o += (counts[e] + 127) & ~127; }
  TK v = tk[t];
  int p0 = offs[v.i0] + atomicAdd(&cursor[v.i0], 1);
  pair_tok[p0] = t; pair_w[p0] = v.w0;
  int p1 = offs[v.i1] + atomicAdd(&cursor[v.i1], 1);
  pair_tok[p1] = t; pair_w[p1] = v.w1;
  inv[t] = make_int2(p0, p1);
}

// ---------------- gather: x fp32 rows -> bf16 xg (expert-sorted) ------------
union Pack8 { __hip_bfloat16 o[8]; uint4 u; };

__global__ __launch_bounds__(256) void gather_kernel(
    const float* __restrict__ x, const int* __restrict__ pair_tok,
    __hip_bfloat16* __restrict__ xg)
{
  int idx = blockIdx.x * 256 + threadIdx.x;   // CAP*128 threads
  int row = idx >> 7;
  int c8  = (idx & 127) << 3;
  int tok = pair_tok[row];                    // pad rows: tok=0, harmless
  const float4* src = reinterpret_cast<const float4*>(x + (size_t)tok * H_DIM + c8);
  float4 a = src[0], b = src[1];
  Pack8 pk;
  pk.o[0] = __float2bfloat16(a.x); pk.o[1] = __float2bfloat16(a.y);
  pk.o[2] = __float2bfloat16(a.z); pk.o[3] = __float2bfloat16(a.w);
  pk.o[4] = __float2bfloat16(b.x); pk.o[5] = __float2bfloat16(b.y);
  pk.o[6] = __float2bfloat16(b.z); pk.o[7] = __float2bfloat16(b.w);
  *reinterpret_cast<uint4*>(xg + (size_t)row * H_DIM + c8) = pk.u;
}

// ---------------- weight convert fp32 -> bf16 (all 3 matrices, fused) -------
__global__ __launch_bounds__(256) void convert3_kernel(
    const float* __restrict__ w1, const float* __restrict__ w3,
    const float* __restrict__ w2, __hip_bfloat16* __restrict__ w1b,
    __hip_bfloat16* __restrict__ w3b, __hip_bfloat16* __restrict__ w2b)
{
  const long long nthr = 3ll * (1 << 22);   // 12,582,912 threads' worth
  for (long long idx = (long long)blockIdx.x * 256 + threadIdx.x; idx < nthr;
       idx += (long long)gridDim.x * 256) {
    int seg = (int)(idx >> 22);
    long long off = (idx & ((1 << 22) - 1)) * 8;
    const float* src = (seg == 0) ? w1 : (seg == 1) ? w3 : w2;
    __hip_bfloat16* dst = (seg == 0) ? w1b : (seg == 1) ? w3b : w2b;
    float4 a = *reinterpret_cast<const float4*>(src + off);
    float4 b = *reinterpret_cast<const float4*>(src + off + 4);
    Pack8 pk;
    pk.o[0] = __float2bfloat16(a.x); pk.o[1] = __float2bfloat16(a.y);
    pk.o[2] = __float2bfloat16(a.z); pk.o[3] = __float2bfloat16(a.w);
    pk.o[4] = __float2bfloat16(b.x); pk.o[5] = __float2bfloat16(b.y);
    pk.o[6] = __float2bfloat16(b.z); pk.o[7] = __float2bfloat16(b.w);
    *reinterpret_cast<uint4*>(dst + off) = pk.u;
  }
}

// ===== LDS input tiles: rows of 64 bf16 = 128B = 8 x 16B slots. T2 swizzle
// (verified 0 conflicts r2-r9): phys slot p at row r holds logical p^(r&7);
// write side pre-swizzles the GLOBAL source slot (rule #21); read side uses
// pslot = (ks*4+lk) ^ (l16&7).
// ===== gemm1 mapping (r7, verified FETCH 1.1GB->305MB): tm globally slow,
// tf fast; per-XCD B working set 4MB = L2-resident, reused across 17 tm.
// ===== gemm2 (r10): split-K + GROUPS OF 4 (tn,kh) per XCD: concurrent
// working set = 4 w2-slices (2MB) + h-tile (1MB) = 3MB <= L2 (r9's 16-fast
// mapping held 8MB of w2 -> L2 thrash). h re-read 4x via L3 (~568MB, cheap).

// ---------------- GEMM1: h = silu(Xg @ w1[e]^T) * (Xg @ w3[e]^T) ------------
// BM=128, BF=64, BK=64. 256 thr = 4 waves (2m x 2n); wave = 64 rows x 32
// f-cols, DUAL acc (w1,w3) = 64 f32/thread.  [unchanged control]
__global__ __launch_bounds__(256, 4) void gemm1_kernel(
    const __hip_bfloat16* __restrict__ xg,
    const __hip_bfloat16* __restrict__ w1b,
    const __hip_bfloat16* __restrict__ w3b,
    const int* __restrict__ counts,
    __hip_bfloat16* __restrict__ h)
{
  __shared__ __hip_bfloat16 smem[16384];        // 32 KB
  __hip_bfloat16* sA  = smem;                   // [128][64]
  __hip_bfloat16* sB1 = smem + 8192;            // [64][64]
  __hip_bfloat16* sB3 = smem + 12288;           // [64][64]

  const int n_  = blockIdx.x;                   // 0..8703
  const int tm  = n_ >> 6;                      // GLOBALLY slow: one expert at a time
  const int tf  = n_ & 63;                      // fast; tf%8 -> XCD residue
  const int e   = tile_expert_of(counts, tm);
  const int tid = threadIdx.x;

  const __hip_bfloat16* A  = xg  + (size_t)tm * 128 * H_DIM;
  const __hip_bfloat16* B1 = w1b + (size_t)e * F_DIM * H_DIM + (size_t)tf * 64 * H_DIM;
  const __hip_bfloat16* B3 = w3b + (size_t)e * F_DIM * H_DIM + (size_t)tf * 64 * H_DIM;

  const int rs  = tid >> 3;                     // 0..31
  const int sl  = tid & 7;
  const int xsl = (sl ^ (rs & 7)) * 8;          // pre-swizzled global slot (elems)
  const int dst = rs * 64 + sl * 8;             // linear LDS dest within 32-row chunk

  const int wv = tid >> 6, lane = tid & 63;
  const int wm = wv >> 1, wn = wv & 1;
  const int l16 = lane & 15, lk = lane >> 4;
  const int ps0 = ((0 + lk) ^ (l16 & 7)) * 8;
  const int ps1 = ((4 + lk) ^ (l16 & 7)) * 8;

  f32x4 acc1[4][2] = {};
  f32x4 acc3[4][2] = {};

  for (int kt = 0; kt < H_DIM / 64; ++kt) {
    __syncthreads();
    const int gk = kt * 64 + xsl;
#pragma unroll
    for (int c = 0; c < 4; ++c)
      gload_lds16(A + (size_t)(rs + 32 * c) * H_DIM + gk, &sA[c * 2048 + dst]);
#pragma unroll
    for (int c = 0; c < 2; ++c) {
      gload_lds16(B1 + (size_t)(rs + 32 * c) * H_DIM + gk, &sB1[c * 2048 + dst]);
      gload_lds16(B3 + (size_t)(rs + 32 * c) * H_DIM + gk, &sB3[c * 2048 + dst]);
    }
    __syncthreads();
#pragma unroll
    for (int ks = 0; ks < 2; ++ks) {
      const int ps = ks ? ps1 : ps0;
      bf16x8 a[4], b1[2], b3[2];
#pragma unroll
      for (int m = 0; m < 4; ++m)
        a[m] = *reinterpret_cast<const bf16x8*>(&sA[(wm * 64 + m * 16 + l16) * 64 + ps]);
#pragma unroll
      for (int nf = 0; nf < 2; ++nf) {
        b1[nf] = *reinterpret_cast<const bf16x8*>(&sB1[(wn * 32 + nf * 16 + l16) * 64 + ps]);
        b3[nf] = *reinterpret_cast<const bf16x8*>(&sB3[(wn * 32 + nf * 16 + l16) * 64 + ps]);
      }
#pragma unroll
      for (int m = 0; m < 4; ++m)
#pragma unroll
        for (int nf = 0; nf < 2; ++nf) {
          acc1[m][nf] = __builtin_amdgcn_mfma_f32_16x16x32_bf16(a[m], b1[nf], acc1[m][nf], 0, 0, 0);
          acc3[m][nf] = __builtin_amdgcn_mfma_f32_16x16x32_bf16(a[m], b3[nf], acc3[m][nf], 0, 0, 0);
        }
    }
  }

  // epilogue: LDS bounce (slot-XOR) -> full-line coalesced stores
  __syncthreads();
#pragma unroll
  for (int m = 0; m < 4; ++m)
#pragma unroll
    for (int nf = 0; nf < 2; ++nf)
#pragma unroll
      for (int j = 0; j < 4; ++j) {
        int row = wm * 64 + m * 16 + lk * 4 + j;   // C/D: col=lane&15, row=(lane>>4)*4+j
        int col = wn * 32 + nf * 16 + l16;
        int phys = row * 64 + (((col >> 3) ^ (row & 7)) << 3) + (col & 7);
        float c1 = acc1[m][nf][j];
        float c3 = acc3[m][nf][j];
        float s  = c1 / (1.f + expf(-c1));
        smem[phys] = __float2bfloat16(s * c3);
      }
  __syncthreads();
  const uint4* s4 = reinterpret_cast<const uint4*>(smem);  // [128 rows][8 slots]
  __hip_bfloat16* hp = h + (size_t)tm * 128 * F_DIM + (size_t)tf * 64;
#pragma unroll
  for (int i = 0; i < 4; ++i) {
    int c = i * 256 + tid;
    int row = c >> 3, sg = c & 7;                // 8x16B = one 128B line per row
    *reinterpret_cast<uint4*>(hp + (size_t)row * F_DIM + sg * 8) =
        s4[row * 8 + (sg ^ (row & 7))];
  }
}

// ---------------- GEMM2 split-K: y[kh][slot] = w * (h @ w2[e]^T)_Khalf ------
// BM=128, BN=128, BK=64, K=2048 per block, kh in {0,1}. 2176 blocks.
// Mapping: XCD = tm%8; per XCD: 4 groups of 4 (tn,kh); within a group, tm
// slow -> concurrent B = 4 slices (2MB) L2-resident across the 17-tm sweep.
__global__ __launch_bounds__(256, 4) void gemm2_kernel(
    const __hip_bfloat16* __restrict__ h,
    const __hip_bfloat16* __restrict__ w2b,
    const int* __restrict__ counts,
    const float* __restrict__ pair_w,
    __hip_bfloat16* __restrict__ y)      // [2][CAP][H_DIM]
{
  __shared__ __hip_bfloat16 smem[16384];        // 32 KB
  __hip_bfloat16* sA = smem;                    // [128][64]
  __hip_bfloat16* sB = smem + 8192;             // [128][64]

  const int n_  = blockIdx.x;                   // 0..2175
  const int r   = n_ & 7;                       // XCD residue
  const int q   = n_ >> 3;                      // 0..271
  const int g   = q / 68;                       // group of 4 (tn,kh)
  const int qq  = q % 68;
  const int tmi = qq >> 2;                      // 0..16
  const int sk  = g * 4 + (qq & 3);             // 0..15
  const int tn  = sk >> 1;                      // 0..7
  const int kh  = sk & 1;                       // K half
  const int tm  = tmi * 8 + r;                  // 0..135; tm%8 == XCD
  const int e   = tile_expert_of(counts, tm);
  const int tid = threadIdx.x;

  const __hip_bfloat16* A = h   + (size_t)tm * 128 * F_DIM + (size_t)kh * 2048;
  const __hip_bfloat16* B = w2b + (size_t)e * H_DIM * F_DIM + (size_t)tn * 128 * F_DIM
                                + (size_t)kh * 2048;

  const int rs  = tid >> 3;                     // 0..31
  const int sl  = tid & 7;
  const int xsl = (sl ^ (rs & 7)) * 8;
  const int dst = rs * 64 + sl * 8;

  const int wv = tid >> 6, lane = tid & 63;
  const int wm = wv >> 1, wn = wv & 1;
  const int l16 = lane & 15, lk = lane >> 4;
  const int ps0 = ((0 + lk) ^ (l16 & 7)) * 8;
  const int ps1 = ((4 + lk) ^ (l16 & 7)) * 8;

  f32x4 acc[4][4] = {};

  for (int kt = 0; kt < 2048 / 64; ++kt) {
    __syncthreads();
    const int gk = kt * 64 + xsl;
#pragma unroll
    for (int c = 0; c < 4; ++c) {
      gload_lds16(A + (size_t)(rs + 32 * c) * F_DIM + gk, &sA[c * 2048 + dst]);
      gload_lds16(B + (size_t)(rs + 32 * c) * F_DIM + gk, &sB[c * 2048 + dst]);
    }
    __syncthreads();
#pragma unroll
    for (int ks = 0; ks < 2; ++ks) {
      const int ps = ks ? ps1 : ps0;
      bf16x8 a[4], b[4];
#pragma unroll
      for (int m = 0; m < 4; ++m)
        a[m] = *reinterpret_cast<const bf16x8*>(&sA[(wm * 64 + m * 16 + l16) * 64 + ps]);
#pragma unroll
      for (int nf = 0; nf < 4; ++nf)
        b[nf] = *reinterpret_cast<const bf16x8*>(&sB[(wn * 64 + nf * 16 + l16) * 64 + ps]);
#pragma unroll
      for (int m = 0; m < 4; ++m)
#pragma unroll
        for (int nf = 0; nf < 4; ++nf)
          acc[m][nf] = __builtin_amdgcn_mfma_f32_16x16x32_bf16(a[m], b[nf], acc[m][nf], 0, 0, 0);
    }
  }

  // epilogue: scale by pair_w, LDS bounce [128][128] bf16 (slot-XOR), store
  __syncthreads();
#pragma unroll
  for (int m = 0; m < 4; ++m)
#pragma unroll
    for (int j = 0; j < 4; ++j) {
      int row  = wm * 64 + m * 16 + lk * 4 + j;
      float w  = pair_w[tm * 128 + row];          // 0 for pad rows
#pragma unroll
      for (int nf = 0; nf < 4; ++nf) {
        int col  = wn * 64 + nf * 16 + l16;
        int phys = row * 128 + (((col >> 3) ^ (row & 7)) << 3) + (col & 7);
        smem[phys] = __float2bfloat16(w * acc[m][nf][j]);
      }
    }
  __syncthreads();
  const uint4* s4 = reinterpret_cast<const uint4*>(smem);  // [128 rows][16 slots]
  __hip_bfloat16* yp = y + (size_t)kh * CAP * H_DIM
                         + (size_t)tm * 128 * H_DIM + (size_t)tn * 128;
#pragma unroll
  for (int i = 0; i < 8; ++i) {
    int c = i * 256 + tid;
    int row = c >> 4, sg = c & 15;               // 16x16B = 256B per row
    *reinterpret_cast<uint4*>(yp + (size_t)row * H_DIM + sg * 8) =
        s4[row * 16 + ((sg & 8) | ((sg ^ row) & 7))];
  }
}

// ---------------- combine: out[t] = sum of 4 bf16 partials ------------------
__global__ __launch_bounds__(256) void combine_kernel(
    const __hip_bfloat16* __restrict__ y, const int2* __restrict__ inv,
    float* __restrict__ out)
{
  int idx = blockIdx.x * 256 + threadIdx.x;   // T*H/8 threads
  int t  = idx >> 7;
  int c8 = (idx & 127) << 3;
  int2 p = inv[t];
  const __hip_bfloat16* y1 = y + (size_t)CAP * H_DIM;
  union { uint4 u; __hip_bfloat16 o[8]; } a, b, c, d;
  a.u = *reinterpret_cast<const uint4*>(y  + (size_t)p.x * H_DIM + c8);
  b.u = *reinterpret_cast<const uint4*>(y  + (size_t)p.y * H_DIM + c8);
  c.u = *reinterpret_cast<const uint4*>(y1 + (size_t)p.x * H_DIM + c8);
  d.u = *reinterpret_cast<const uint4*>(y1 + (size_t)p.y * H_DIM + c8);
  float* op = out + (size_t)t * H_DIM + c8;
#pragma unroll
  for (int i = 0; i < 8; ++i)
    op[i] = __bfloat162float(a.o[i]) + __bfloat162float(b.o[i]) +
            __bfloat162float(c.o[i]) + __bfloat162float(d.o[i]);
}

// ---------------- workspace layout ------------------------------------------
#define WS_COUNTS   0
#define WS_CURSOR   32
#define WS_TK       1024      // 131072
#define WS_PAIRTOK  132096    // 69632
#define WS_PAIRW    201728    // 69632
#define WS_ZERO_BYTES 271360  // counts..pair_w zeroed per call
#define WS_INV      271360    // int2[8192] = 65536 (fully written each call)
#define WS_XG       336896ll
#define WS_W1       (WS_XG + 35651584ll)    //  35988480
#define WS_W3       (WS_W1 + 67108864ll)    // 103097344
#define WS_W2       (WS_W3 + 67108864ll)    // 170206208
#define WS_H        (WS_W2 + 67108864ll)    // 237315072; h = 142.6 MB
// y [2][CAP][H] bf16 = 71.3 MB aliases xg (35.6) + w1b (67.1): both dead
// after gemm1, both fully rewritten every call before gemm1 runs.
#define WS_Y        WS_XG

extern "C" void kernel_launch(void* const* d_in, const int* in_sizes, int n_in,
                              void* d_out, int out_size, void* d_ws, size_t ws_size,
                              hipStream_t stream) {
  const float* x  = (const float*)d_in[0];
  const float* gw = (const float*)d_in[1];
  const float* w1 = (const float*)d_in[2];
  const float* w3 = (const float*)d_in[3];
  const float* w2 = (const float*)d_in[4];
  float* out    = (float*)d_out;
  float* logits = out + (size_t)T_TOK * H_DIM;

  char* ws = (char*)d_ws;
  int*   counts   = (int*)(ws + WS_COUNTS);
  int*   cursor   = (int*)(ws + WS_CURSOR);
  TK*    tk       = (TK*)(ws + WS_TK);
  int*   pair_tok = (int*)(ws + WS_PAIRTOK);
  float* pair_w   = (float*)(ws + WS_PAIRW);
  int2*  inv      = (int2*)(ws + WS_INV);
  __hip_bfloat16* xg  = (__hip_bfloat16*)(ws + WS_XG);
  __hip_bfloat16* w1b = (__hip_bfloat16*)(ws + WS_W1);
  __hip_bfloat16* w3b = (__hip_bfloat16*)(ws + WS_W3);
  __hip_bfloat16* w2b = (__hip_bfloat16*)(ws + WS_W2);
  __hip_bfloat16* hbuf = (__hip_bfloat16*)(ws + WS_H);
  __hip_bfloat16* ybuf = (__hip_bfloat16*)(ws + WS_Y);

  hipMemsetAsync(d_ws, 0, WS_ZERO_BYTES, stream);

  convert3_kernel<<<8192, 256, 0, stream>>>(w1, w3, w2, w1b, w3b, w2b);

  router_kernel<<<T_TOK / 4, 256, 0, stream>>>(x, gw, logits, counts, tk);
  scatter_kernel<<<T_TOK / 256, 256, 0, stream>>>(tk, counts, cursor,
                                                  pair_tok, pair_w, inv);
  gather_kernel<<<(CAP * 128) / 256, 256, 0, stream>>>(x, pair_tok, xg);

  gemm1_kernel<<<CT128 * (F_DIM / 64), 256, 0, stream>>>(
      xg, w1b, w3b, counts, hbuf);
  gemm2_kernel<<<CT128 * 16, 256, 0, stream>>>(
      hbuf, w2b, counts, pair_w, ybuf);
  combine_kernel<<<(T_TOK * H_DIM / 8) / 256, 256, 0, stream>>>(ybuf, inv, out);
}

// Round 11
// 866.432 us; speedup vs baseline: 1.0507x; 1.0507x over previous
//
#include <hip/hip_runtime.h>
#include <hip/hip_bf16.h>
#include <stdint.h>

#define T_TOK 8192
#define H_DIM 1024
#define F_DIM 4096
#define NEXP  8
#define CAP        17408   // 16384 + 8*128 worst-case 128-aligned padding
#define CT128      136     // CAP/128

typedef __attribute__((ext_vector_type(8))) short bf16x8;
typedef __attribute__((ext_vector_type(4))) float f32x4;

#define AS1 __attribute__((address_space(1)))
#define AS3 __attribute__((address_space(3)))

__device__ __forceinline__ void gload_lds16(const void* g, void* l) {
  __builtin_amdgcn_global_load_lds((const AS1 void*)g, (AS3 void*)l, 16, 0, 0);
}

// expert of a 128-row tile, from counts (128-aligned segments)
__device__ __forceinline__ int tile_expert_of(const int* counts, int tm) {
  int row = tm * 128, off = 0, e = NEXP - 1;
#pragma unroll
  for (int k = 0; k < NEXP; ++k) {
    int nxt = off + ((counts[k] + 127) & ~127);
    if (row >= off && row < nxt) { e = k; break; }
    off = nxt;
  }
  return e;
}

struct TK { int i0, i1; float w0, w1; };

// ---------------- router: fp32 logits, softmax, top-2, renorm ----------------
__global__ __launch_bounds__(256) void router_kernel(
    const float* __restrict__ x, const float* __restrict__ gw,
    float* __restrict__ logits, int* __restrict__ counts, TK* __restrict__ tk)
{
  const int lane = threadIdx.x & 63;
  const int t = blockIdx.x * 4 + (threadIdx.x >> 6);
  const float* xp = x + (size_t)t * H_DIM;
  float xr[16];
#pragma unroll
  for (int i = 0; i < 16; ++i) xr[i] = xp[lane + i * 64];
  float lg[NEXP];
#pragma unroll
  for (int e = 0; e < NEXP; ++e) {
    const float* gp = gw + e * H_DIM;
    float acc = 0.f;
#pragma unroll
    for (int i = 0; i < 16; ++i) acc += xr[i] * gp[lane + i * 64];
#pragma unroll
    for (int s = 32; s > 0; s >>= 1) acc += __shfl_xor(acc, s, 64);
    lg[e] = acc;
  }
  if (lane < NEXP) logits[(size_t)t * NEXP + lane] = lg[lane];
  if (lane == 0) {
    int i0 = 0; float m0 = lg[0];
#pragma unroll
    for (int e = 1; e < NEXP; ++e) if (lg[e] > m0) { m0 = lg[e]; i0 = e; }
    int i1 = -1; float m1 = -1e30f;
#pragma unroll
    for (int e = 0; e < NEXP; ++e) if (e != i0 && lg[e] > m1) { m1 = lg[e]; i1 = e; }
    float r = expf(m1 - m0);            // top-2 renormalized softmax
    float w0 = 1.f / (1.f + r);
    float w1 = r / (1.f + r);
    TK v; v.i0 = i0; v.i1 = i1; v.w0 = w0; v.w1 = w1;
    tk[t] = v;
    atomicAdd(&counts[i0], 1);
    atomicAdd(&counts[i1], 1);
  }
}

// ---------------- scatter: token -> slot (offsets computed inline) ----------
__global__ __launch_bounds__(256) void scatter_kernel(
    const TK* __restrict__ tk, const int* __restrict__ counts,
    int* __restrict__ cursor, int* __restrict__ pair_tok,
    float* __restrict__ pair_w, int2* __restrict__ inv)
{
  int t = blockIdx.x * 256 + threadIdx.x;
  if (t >= T_TOK) return;
  int offs[NEXP];
  int o = 0;
#pragma unroll
  for (int e = 0; e < NEXP; ++e) { offs[e] = o; o += (counts[e] + 127) & ~127; }
  TK v = tk[t];
  int p0 = offs[v.i0] + atomicAdd(&cursor[v.i0], 1);
  pair_tok[p0] = t; pair_w[p0] = v.w0;
  int p1 = offs[v.i1] + atomicAdd(&cursor[v.i1], 1);
  pair_tok[p1] = t; pair_w[p1] = v.w1;
  inv[t] = make_int2(p0, p1);
}

// ---------------- gather: x fp32 rows -> bf16 xg (expert-sorted) ------------
union Pack8 { __hip_bfloat16 o[8]; uint4 u; };

__global__ __launch_bounds__(256) void gather_kernel(
    const float* __restrict__ x, const int* __restrict__ pair_tok,
    __hip_bfloat16* __restrict__ xg)
{
  int idx = blockIdx.x * 256 + threadIdx.x;   // CAP*128 threads
  int row = idx >> 7;
  int c8  = (idx & 127) << 3;
  int tok = pair_tok[row];                    // pad rows: tok=0, harmless
  const float4* src = reinterpret_cast<const float4*>(x + (size_t)tok * H_DIM + c8);
  float4 a = src[0], b = src[1];
  Pack8 pk;
  pk.o[0] = __float2bfloat16(a.x); pk.o[1] = __float2bfloat16(a.y);
  pk.o[2] = __float2bfloat16(a.z); pk.o[3] = __float2bfloat16(a.w);
  pk.o[4] = __float2bfloat16(b.x); pk.o[5] = __float2bfloat16(b.y);
  pk.o[6] = __float2bfloat16(b.z); pk.o[7] = __float2bfloat16(b.w);
  *reinterpret_cast<uint4*>(xg + (size_t)row * H_DIM + c8) = pk.u;
}

// ---------------- weight convert fp32 -> bf16 (all 3 matrices, fused) -------
// Launched LAST before gemm1 so the bf16 weight stream (201 MB) is the
// freshest content in L3 when gemm1 reads it (r11).
__global__ __launch_bounds__(256) void convert3_kernel(
    const float* __restrict__ w1, const float* __restrict__ w3,
    const float* __restrict__ w2, __hip_bfloat16* __restrict__ w1b,
    __hip_bfloat16* __restrict__ w3b, __hip_bfloat16* __restrict__ w2b)
{
  const long long nthr = 3ll * (1 << 22);   // 12,582,912 threads' worth
  for (long long idx = (long long)blockIdx.x * 256 + threadIdx.x; idx < nthr;
       idx += (long long)gridDim.x * 256) {
    int seg = (int)(idx >> 22);
    long long off = (idx & ((1 << 22) - 1)) * 8;
    const float* src = (seg == 0) ? w1 : (seg == 1) ? w3 : w2;
    __hip_bfloat16* dst = (seg == 0) ? w1b : (seg == 1) ? w3b : w2b;
    float4 a = *reinterpret_cast<const float4*>(src + off);
    float4 b = *reinterpret_cast<const float4*>(src + off + 4);
    Pack8 pk;
    pk.o[0] = __float2bfloat16(a.x); pk.o[1] = __float2bfloat16(a.y);
    pk.o[2] = __float2bfloat16(a.z); pk.o[3] = __float2bfloat16(a.w);
    pk.o[4] = __float2bfloat16(b.x); pk.o[5] = __float2bfloat16(b.y);
    pk.o[6] = __float2bfloat16(b.z); pk.o[7] = __float2bfloat16(b.w);
    *reinterpret_cast<uint4*>(dst + off) = pk.u;
  }
}

// ===== LDS input tiles: rows of 64 bf16 = 128B = 8 x 16B slots. T2 swizzle
// (verified 0 conflicts r2-r10): phys slot p at row r holds logical p^(r&7);
// write side pre-swizzles the GLOBAL source slot (rule #21); read side uses
// pslot = (ks*4+lk) ^ (l16&7).
// ===== gemm1 mapping (r7, verified FETCH 1.1GB->305MB): tm globally slow,
// tf fast; per-XCD B working set 4MB = L2-resident, reused across 17 tm.
// ===== gemm2 mapping: r9's flat split-K order (measured best, 869 total);
// r10's "4-group" remap regressed +41us — reverted.

// ---------------- GEMM1: h = silu(Xg @ w1[e]^T) * (Xg @ w3[e]^T) ------------
// BM=128, BF=64, BK=64. 256 thr = 4 waves (2m x 2n); wave = 64 rows x 32
// f-cols, DUAL acc (w1,w3) = 64 f32/thread.  [unchanged control]
__global__ __launch_bounds__(256, 4) void gemm1_kernel(
    const __hip_bfloat16* __restrict__ xg,
    const __hip_bfloat16* __restrict__ w1b,
    const __hip_bfloat16* __restrict__ w3b,
    const int* __restrict__ counts,
    __hip_bfloat16* __restrict__ h)
{
  __shared__ __hip_bfloat16 smem[16384];        // 32 KB
  __hip_bfloat16* sA  = smem;                   // [128][64]
  __hip_bfloat16* sB1 = smem + 8192;            // [64][64]
  __hip_bfloat16* sB3 = smem + 12288;           // [64][64]

  const int n_  = blockIdx.x;                   // 0..8703
  const int tm  = n_ >> 6;                      // GLOBALLY slow: one expert at a time
  const int tf  = n_ & 63;                      // fast; tf%8 -> XCD residue
  const int e   = tile_expert_of(counts, tm);
  const int tid = threadIdx.x;

  const __hip_bfloat16* A  = xg  + (size_t)tm * 128 * H_DIM;
  const __hip_bfloat16* B1 = w1b + (size_t)e * F_DIM * H_DIM + (size_t)tf * 64 * H_DIM;
  const __hip_bfloat16* B3 = w3b + (size_t)e * F_DIM * H_DIM + (size_t)tf * 64 * H_DIM;

  const int rs  = tid >> 3;                     // 0..31
  const int sl  = tid & 7;
  const int xsl = (sl ^ (rs & 7)) * 8;          // pre-swizzled global slot (elems)
  const int dst = rs * 64 + sl * 8;             // linear LDS dest within 32-row chunk

  const int wv = tid >> 6, lane = tid & 63;
  const int wm = wv >> 1, wn = wv & 1;
  const int l16 = lane & 15, lk = lane >> 4;
  const int ps0 = ((0 + lk) ^ (l16 & 7)) * 8;
  const int ps1 = ((4 + lk) ^ (l16 & 7)) * 8;

  f32x4 acc1[4][2] = {};
  f32x4 acc3[4][2] = {};

  for (int kt = 0; kt < H_DIM / 64; ++kt) {
    __syncthreads();
    const int gk = kt * 64 + xsl;
#pragma unroll
    for (int c = 0; c < 4; ++c)
      gload_lds16(A + (size_t)(rs + 32 * c) * H_DIM + gk, &sA[c * 2048 + dst]);
#pragma unroll
    for (int c = 0; c < 2; ++c) {
      gload_lds16(B1 + (size_t)(rs + 32 * c) * H_DIM + gk, &sB1[c * 2048 + dst]);
      gload_lds16(B3 + (size_t)(rs + 32 * c) * H_DIM + gk, &sB3[c * 2048 + dst]);
    }
    __syncthreads();
#pragma unroll
    for (int ks = 0; ks < 2; ++ks) {
      const int ps = ks ? ps1 : ps0;
      bf16x8 a[4], b1[2], b3[2];
#pragma unroll
      for (int m = 0; m < 4; ++m)
        a[m] = *reinterpret_cast<const bf16x8*>(&sA[(wm * 64 + m * 16 + l16) * 64 + ps]);
#pragma unroll
      for (int nf = 0; nf < 2; ++nf) {
        b1[nf] = *reinterpret_cast<const bf16x8*>(&sB1[(wn * 32 + nf * 16 + l16) * 64 + ps]);
        b3[nf] = *reinterpret_cast<const bf16x8*>(&sB3[(wn * 32 + nf * 16 + l16) * 64 + ps]);
      }
#pragma unroll
      for (int m = 0; m < 4; ++m)
#pragma unroll
        for (int nf = 0; nf < 2; ++nf) {
          acc1[m][nf] = __builtin_amdgcn_mfma_f32_16x16x32_bf16(a[m], b1[nf], acc1[m][nf], 0, 0, 0);
          acc3[m][nf] = __builtin_amdgcn_mfma_f32_16x16x32_bf16(a[m], b3[nf], acc3[m][nf], 0, 0, 0);
        }
    }
  }

  // epilogue: LDS bounce (slot-XOR) -> full-line coalesced stores
  __syncthreads();
#pragma unroll
  for (int m = 0; m < 4; ++m)
#pragma unroll
    for (int nf = 0; nf < 2; ++nf)
#pragma unroll
      for (int j = 0; j < 4; ++j) {
        int row = wm * 64 + m * 16 + lk * 4 + j;   // C/D: col=lane&15, row=(lane>>4)*4+j
        int col = wn * 32 + nf * 16 + l16;
        int phys = row * 64 + (((col >> 3) ^ (row & 7)) << 3) + (col & 7);
        float c1 = acc1[m][nf][j];
        float c3 = acc3[m][nf][j];
        float s  = c1 / (1.f + expf(-c1));
        smem[phys] = __float2bfloat16(s * c3);
      }
  __syncthreads();
  const uint4* s4 = reinterpret_cast<const uint4*>(smem);  // [128 rows][8 slots]
  __hip_bfloat16* hp = h + (size_t)tm * 128 * F_DIM + (size_t)tf * 64;
#pragma unroll
  for (int i = 0; i < 4; ++i) {
    int c = i * 256 + tid;
    int row = c >> 3, sg = c & 7;                // 8x16B = one 128B line per row
    *reinterpret_cast<uint4*>(hp + (size_t)row * F_DIM + sg * 8) =
        s4[row * 8 + (sg ^ (row & 7))];
  }
}

// ---------------- GEMM2 split-K: y[kh][slot] = w * (h @ w2[e]^T)_Khalf ------
// BM=128, BN=128, BK=64, K=2048 per block, kh in {0,1}. 2176 blocks.
// r9 mapping (measured best): XCD = tm%8; per XCD, tm slow, (tn,kh) fast.
__global__ __launch_bounds__(256, 4) void gemm2_kernel(
    const __hip_bfloat16* __restrict__ h,
    const __hip_bfloat16* __restrict__ w2b,
    const int* __restrict__ counts,
    const float* __restrict__ pair_w,
    __hip_bfloat16* __restrict__ y)      // [2][CAP][H_DIM]
{
  __shared__ __hip_bfloat16 smem[16384];        // 32 KB
  __hip_bfloat16* sA = smem;                    // [128][64]
  __hip_bfloat16* sB = smem + 8192;             // [128][64]

  const int n_  = blockIdx.x;                   // 0..2175
  const int r   = n_ & 7;                       // XCD residue
  const int q   = n_ >> 3;                      // 0..271
  const int tm  = (q >> 4) * 8 + r;             // 0..135; tm%8 == XCD
  const int s_  = q & 15;
  const int tn  = s_ >> 1;                      // 0..7
  const int kh  = s_ & 1;                       // K half
  const int e   = tile_expert_of(counts, tm);
  const int tid = threadIdx.x;

  const __hip_bfloat16* A = h   + (size_t)tm * 128 * F_DIM + (size_t)kh * 2048;
  const __hip_bfloat16* B = w2b + (size_t)e * H_DIM * F_DIM + (size_t)tn * 128 * F_DIM
                                + (size_t)kh * 2048;

  const int rs  = tid >> 3;                     // 0..31
  const int sl  = tid & 7;
  const int xsl = (sl ^ (rs & 7)) * 8;
  const int dst = rs * 64 + sl * 8;

  const int wv = tid >> 6, lane = tid & 63;
  const int wm = wv >> 1, wn = wv & 1;
  const int l16 = lane & 15, lk = lane >> 4;
  const int ps0 = ((0 + lk) ^ (l16 & 7)) * 8;
  const int ps1 = ((4 + lk) ^ (l16 & 7)) * 8;

  f32x4 acc[4][4] = {};

  for (int kt = 0; kt < 2048 / 64; ++kt) {
    __syncthreads();
    const int gk = kt * 64 + xsl;
#pragma unroll
    for (int c = 0; c < 4; ++c) {
      gload_lds16(A + (size_t)(rs + 32 * c) * F_DIM + gk, &sA[c * 2048 + dst]);
      gload_lds16(B + (size_t)(rs + 32 * c) * F_DIM + gk, &sB[c * 2048 + dst]);
    }
    __syncthreads();
#pragma unroll
    for (int ks = 0; ks < 2; ++ks) {
      const int ps = ks ? ps1 : ps0;
      bf16x8 a[4], b[4];
#pragma unroll
      for (int m = 0; m < 4; ++m)
        a[m] = *reinterpret_cast<const bf16x8*>(&sA[(wm * 64 + m * 16 + l16) * 64 + ps]);
#pragma unroll
      for (int nf = 0; nf < 4; ++nf)
        b[nf] = *reinterpret_cast<const bf16x8*>(&sB[(wn * 64 + nf * 16 + l16) * 64 + ps]);
#pragma unroll
      for (int m = 0; m < 4; ++m)
#pragma unroll
        for (int nf = 0; nf < 4; ++nf)
          acc[m][nf] = __builtin_amdgcn_mfma_f32_16x16x32_bf16(a[m], b[nf], acc[m][nf], 0, 0, 0);
    }
  }

  // epilogue: scale by pair_w, LDS bounce [128][128] bf16 (slot-XOR), store
  __syncthreads();
#pragma unroll
  for (int m = 0; m < 4; ++m)
#pragma unroll
    for (int j = 0; j < 4; ++j) {
      int row  = wm * 64 + m * 16 + lk * 4 + j;
      float w  = pair_w[tm * 128 + row];          // 0 for pad rows
#pragma unroll
      for (int nf = 0; nf < 4; ++nf) {
        int col  = wn * 64 + nf * 16 + l16;
        int phys = row * 128 + (((col >> 3) ^ (row & 7)) << 3) + (col & 7);
        smem[phys] = __float2bfloat16(w * acc[m][nf][j]);
      }
    }
  __syncthreads();
  const uint4* s4 = reinterpret_cast<const uint4*>(smem);  // [128 rows][16 slots]
  __hip_bfloat16* yp = y + (size_t)kh * CAP * H_DIM
                         + (size_t)tm * 128 * H_DIM + (size_t)tn * 128;
#pragma unroll
  for (int i = 0; i < 8; ++i) {
    int c = i * 256 + tid;
    int row = c >> 4, sg = c & 15;               // 16x16B = 256B per row
    *reinterpret_cast<uint4*>(yp + (size_t)row * H_DIM + sg * 8) =
        s4[row * 16 + ((sg & 8) | ((sg ^ row) & 7))];
  }
}

// ---------------- combine: out[t] = sum of 4 bf16 partials ------------------
__global__ __launch_bounds__(256) void combine_kernel(
    const __hip_bfloat16* __restrict__ y, const int2* __restrict__ inv,
    float* __restrict__ out)
{
  int idx = blockIdx.x * 256 + threadIdx.x;   // T*H/8 threads
  int t  = idx >> 7;
  int c8 = (idx & 127) << 3;
  int2 p = inv[t];
  const __hip_bfloat16* y1 = y + (size_t)CAP * H_DIM;
  union { uint4 u; __hip_bfloat16 o[8]; } a, b, c, d;
  a.u = *reinterpret_cast<const uint4*>(y  + (size_t)p.x * H_DIM + c8);
  b.u = *reinterpret_cast<const uint4*>(y  + (size_t)p.y * H_DIM + c8);
  c.u = *reinterpret_cast<const uint4*>(y1 + (size_t)p.x * H_DIM + c8);
  d.u = *reinterpret_cast<const uint4*>(y1 + (size_t)p.y * H_DIM + c8);
  float* op = out + (size_t)t * H_DIM + c8;
#pragma unroll
  for (int i = 0; i < 8; ++i)
    op[i] = __bfloat162float(a.o[i]) + __bfloat162float(b.o[i]) +
            __bfloat162float(c.o[i]) + __bfloat162float(d.o[i]);
}

// ---------------- workspace layout ------------------------------------------
#define WS_COUNTS   0
#define WS_CURSOR   32
#define WS_TK       1024      // 131072
#define WS_PAIRTOK  132096    // 69632
#define WS_PAIRW    201728    // 69632
#define WS_ZERO_BYTES 271360  // counts..pair_w zeroed per call
#define WS_INV      271360    // int2[8192] = 65536 (fully written each call)
#define WS_XG       336896ll
#define WS_W1       (WS_XG + 35651584ll)    //  35988480
#define WS_W3       (WS_W1 + 67108864ll)    // 103097344
#define WS_W2       (WS_W3 + 67108864ll)    // 170206208
#define WS_H        (WS_W2 + 67108864ll)    // 237315072; h = 142.6 MB
// y [2][CAP][H] bf16 = 71.3 MB aliases xg (35.6) + w1b (67.1): both dead
// after gemm1, both fully rewritten every call before gemm1 runs.
#define WS_Y        WS_XG

extern "C" void kernel_launch(void* const* d_in, const int* in_sizes, int n_in,
                              void* d_out, int out_size, void* d_ws, size_t ws_size,
                              hipStream_t stream) {
  const float* x  = (const float*)d_in[0];
  const float* gw = (const float*)d_in[1];
  const float* w1 = (const float*)d_in[2];
  const float* w3 = (const float*)d_in[3];
  const float* w2 = (const float*)d_in[4];
  float* out    = (float*)d_out;
  float* logits = out + (size_t)T_TOK * H_DIM;

  char* ws = (char*)d_ws;
  int*   counts   = (int*)(ws + WS_COUNTS);
  int*   cursor   = (int*)(ws + WS_CURSOR);
  TK*    tk       = (TK*)(ws + WS_TK);
  int*   pair_tok = (int*)(ws + WS_PAIRTOK);
  float* pair_w   = (float*)(ws + WS_PAIRW);
  int2*  inv      = (int2*)(ws + WS_INV);
  __hip_bfloat16* xg  = (__hip_bfloat16*)(ws + WS_XG);
  __hip_bfloat16* w1b = (__hip_bfloat16*)(ws + WS_W1);
  __hip_bfloat16* w3b = (__hip_bfloat16*)(ws + WS_W3);
  __hip_bfloat16* w2b = (__hip_bfloat16*)(ws + WS_W2);
  __hip_bfloat16* hbuf = (__hip_bfloat16*)(ws + WS_H);
  __hip_bfloat16* ybuf = (__hip_bfloat16*)(ws + WS_Y);

  hipMemsetAsync(d_ws, 0, WS_ZERO_BYTES, stream);

  // token-side prep first...
  router_kernel<<<T_TOK / 4, 256, 0, stream>>>(x, gw, logits, counts, tk);
  scatter_kernel<<<T_TOK / 256, 256, 0, stream>>>(tk, counts, cursor,
                                                  pair_tok, pair_w, inv);
  gather_kernel<<<(CAP * 128) / 256, 256, 0, stream>>>(x, pair_tok, xg);

  // ...then weight convert immediately before gemm1 (bf16 weights freshest in L3)
  convert3_kernel<<<8192, 256, 0, stream>>>(w1, w3, w2, w1b, w3b, w2b);

  gemm1_kernel<<<CT128 * (F_DIM / 64), 256, 0, stream>>>(
      xg, w1b, w3b, counts, hbuf);
  gemm2_kernel<<<CT128 * 16, 256, 0, stream>>>(
      hbuf, w2b, counts, pair_w, ybuf);
  combine_kernel<<<(T_TOK * H_DIM / 8) / 256, 256, 0, stream>>>(ybuf, inv, out);
}